// Round 9
// baseline (82.116 us; speedup 1.0000x reference)
//
#include <hip/hip_runtime.h>
#include <float.h>

#define BB 16
#define CC 64
#define NN 2048
#define KNN 3
#define COUT 64
#define SPL 8   // candidate-range splits; 256 candidates/split -> 8-bit local idx

typedef _Float16 half8 __attribute__((ext_vector_type(8)));
typedef float f32x16 __attribute__((ext_vector_type(16)));

union u4h8 { uint4 v; half8 h; };

// async global->LDS, 16B per lane, wave-uniform LDS base (HW adds lane*16)
__device__ __forceinline__ void gl_lds16(const void* g, void* l) {
    __builtin_amdgcn_global_load_lds(
        (const __attribute__((address_space(1))) unsigned*)g,
        (__attribute__((address_space(3))) unsigned*)l, 16, 0, 0);
}

// ---------------------------------------------------------------------------
// K1: from x[b][c][n] produce:
//   xe[b][ct][kblk][lane] (16B fp16x8 MFMA fragments of ext=[hi|lo], K=128)
//   anc[b][ct][l<32] (packed fp16 pair (-nc/2 hi, -nc/2 lo))
// Fragment convention: row m = lane&31, k = kblk*16 + 8*(lane>>5) + j.
// kblk 0..3 = hi(x[c]) (c = k), kblk 4..7 = lo residual (c = k-64).
// ---------------------------------------------------------------------------
__global__ __launch_bounds__(256) void k_prep(const float* __restrict__ x,
                                              uint4* __restrict__ xe,
                                              unsigned* __restrict__ anc) {
    __shared__ float t[64][65];
    __shared__ float nsh[64];
    const int b = blockIdx.x;
    const int n0 = blockIdx.y * 64;
    const int tid = threadIdx.x;
    const int ln = tid & 63, g = tid >> 6;
#pragma unroll
    for (int i = 0; i < 16; ++i) {
        const int c = g + 4 * i;
        t[c][ln] = x[((size_t)b * CC + c) * NN + n0 + ln];
    }
    __syncthreads();
    if (tid < 64) {
        float s = 0.f;
#pragma unroll
        for (int c = 0; c < 64; ++c) s = fmaf(t[c][tid], t[c][tid], s);
        nsh[tid] = s;
    }
    // fragment packing: 1024 16B chunks per 64-point group
#pragma unroll
    for (int i = 0; i < 4; ++i) {
        const int cid = tid + 256 * i;
        const int lane = cid & 63;
        const int kblk = (cid >> 6) & 7;
        const int ctl = cid >> 9;               // 0..1
        const int m = ctl * 32 + (lane & 31);   // local point
        const int khalf = (lane >> 5) * 8;
        union { uint4 v; _Float16 h[8]; } pk;
#pragma unroll
        for (int j = 0; j < 8; ++j) {
            const int kg = kblk * 16 + khalf + j;
            const int ch = kg & 63;
            const float f = t[ch][m];
            const _Float16 hi = (_Float16)f;
            pk.h[j] = (kg < 64) ? hi : (_Float16)(f - (float)hi);
        }
        const int ct = (n0 >> 5) + ctl;
        xe[((size_t)(b * 64 + ct) * 8 + kblk) * 64 + lane] = pk.v;
    }
    __syncthreads();
    if (tid < 64) {
        const int ctl = tid >> 5, l = tid & 31;
        const int ct = (n0 >> 5) + ctl;
        const float h = -0.5f * nsh[ctl * 32 + l];
        const _Float16 a0 = (_Float16)h;
        const _Float16 a1 = (_Float16)(h - (float)a0);
        union { unsigned u; _Float16 hh[2]; } cu;
        cu.hh[0] = a0; cu.hh[1] = a1;
        anc[(size_t)(b * 64 + ct) * 32 + l] = cu.u;
    }
}

// ---------------------------------------------------------------------------
// K1b: pack W into fp16 B-fragments. Wf[((kk*2+ct2)*4+kb)*64 + lane]:
// co = ct2*32 + (lane&31), c = kb*16 + 8*(lane>>5) + j, value = fp16(W[co][c][kk])
// ---------------------------------------------------------------------------
__global__ __launch_bounds__(256) void k_wprep(const float* __restrict__ W,
                                               uint4* __restrict__ Wf) {
    const int tid = threadIdx.x;
#pragma unroll
    for (int i = 0; i < 6; ++i) {
        const int id = tid + 256 * i;
        const int l = id & 63;
        const int kb = (id >> 6) & 3;
        const int ct2 = (id >> 8) & 1;
        const int kk = id >> 9;
        const int co = ct2 * 32 + (l & 31);
        union { uint4 v; _Float16 h[8]; } pk;
#pragma unroll
        for (int j = 0; j < 8; ++j) {
            const int c = kb * 16 + 8 * (l >> 5) + j;
            pk.h[j] = (_Float16)W[(co * CC + c) * KNN + kk];
        }
        Wf[id] = pk.v;
    }
}

// ---------------------------------------------------------------------------
// K2: MFMA top-3, LDS-staged candidates. Block = 4 waves × 2 query groups;
// all waves share the candidate tile, staged 8KB/tile double-buffered via
// global_load_lds (2 calls/wave). Per tile per wave: 26 MFMA
// (hihi 8, hilo 8, lohi 8, norm 2 — lolo dropped: <1e-6 of key scale).
// Rank by LARGEST acc = dot - nc/2. Store LOCAL idx (8-bit) packed.
// ---------------------------------------------------------------------------
__global__ __launch_bounds__(256, 4) void k_top3(const uint4* __restrict__ xe,
                                                 const unsigned* __restrict__ anc,
                                                 uint4* __restrict__ pk) {
    __shared__ uint4 buf[2][8][64];  // 2 x 8KB candidate tiles
    const int tid = threadIdx.x;
    const int lane = tid & 63;
    const int w = tid >> 6;
    const int wq = blockIdx.x * 4 + w;           // 0..31
    const int qgA = wq * 2, qgB = wq * 2 + 1;
    const int s = blockIdx.y;
    const int b = blockIdx.z;

    half8 bqA[8], bqB[8];
#pragma unroll
    for (int kb = 0; kb < 8; ++kb) {
        u4h8 tA, tB;
        tA.v = xe[((size_t)(b * 64 + qgA) * 8 + kb) * 64 + lane];
        tB.v = xe[((size_t)(b * 64 + qgB) * 8 + kb) * 64 + lane];
        bqA[kb] = tA.h; bqB[kb] = tB.h;
    }
    half8 bnc = {};
    if (lane < 32) { bnc[0] = (_Float16)1.0f; bnc[1] = (_Float16)1.0f; }

    float kA0 = -FLT_MAX, kA1 = -FLT_MAX, kA2 = -FLT_MAX;
    float kB0 = -FLT_MAX, kB1 = -FLT_MAX, kB2 = -FLT_MAX;
    int iA0 = -1, iA1 = -1, iA2 = -1;
    int iB0 = -1, iB1 = -1, iB2 = -1;
    const int hi4 = (lane >> 5) * 4;

    constexpr int TILES = NN / 32 / SPL;  // 8
    const int ct0 = s * TILES;
    const uint4* xb = xe + (size_t)(b * 64) * 512;  // tile stride = 8*64
    const int kb0 = 2 * w, kb1 = 2 * w + 1;         // this wave's staging slice

    // prologue: stage tile 0
    gl_lds16(xb + ((size_t)ct0 * 8 + kb0) * 64 + lane, &buf[0][kb0][0]);
    gl_lds16(xb + ((size_t)ct0 * 8 + kb1) * 64 + lane, &buf[0][kb1][0]);
    __syncthreads();

#pragma unroll
    for (int t = 0; t < TILES; ++t) {
        const int bi = t & 1;
        const int ct = ct0 + t;
        if (t + 1 < TILES) {  // stage next tile while computing this one
            gl_lds16(xb + ((size_t)(ct + 1) * 8 + kb0) * 64 + lane, &buf[bi ^ 1][kb0][0]);
            gl_lds16(xb + ((size_t)(ct + 1) * 8 + kb1) * 64 + lane, &buf[bi ^ 1][kb1][0]);
        }
        const unsigned av_u = anc[(size_t)(b * 64 + ct) * 32 + (lane & 31)];

        f32x16 accA = {}, accB = {};
        {   // hi fragments: feed hihi + hilo (16 MFMA)
            u4h8 ah[4];
#pragma unroll
            for (int kb = 0; kb < 4; ++kb) ah[kb].v = buf[bi][kb][lane];
#pragma unroll
            for (int kb = 0; kb < 4; ++kb) {
                accA = __builtin_amdgcn_mfma_f32_32x32x16_f16(ah[kb].h, bqA[kb], accA, 0, 0, 0);
                accB = __builtin_amdgcn_mfma_f32_32x32x16_f16(ah[kb].h, bqB[kb], accB, 0, 0, 0);
            }
#pragma unroll
            for (int kb = 0; kb < 4; ++kb) {
                accA = __builtin_amdgcn_mfma_f32_32x32x16_f16(ah[kb].h, bqA[kb + 4], accA, 0, 0, 0);
                accB = __builtin_amdgcn_mfma_f32_32x32x16_f16(ah[kb].h, bqB[kb + 4], accB, 0, 0, 0);
            }
        }
        {   // lo fragments: feed lohi (8 MFMA) + norm fold (2)
            u4h8 al[4];
#pragma unroll
            for (int kb = 0; kb < 4; ++kb) al[kb].v = buf[bi][4 + kb][lane];
#pragma unroll
            for (int kb = 0; kb < 4; ++kb) {
                accA = __builtin_amdgcn_mfma_f32_32x32x16_f16(al[kb].h, bqA[kb], accA, 0, 0, 0);
                accB = __builtin_amdgcn_mfma_f32_32x32x16_f16(al[kb].h, bqB[kb], accB, 0, 0, 0);
            }
            half8 av = {};
            union { unsigned u; _Float16 hh[2]; } cu;
            cu.u = av_u;
            av[0] = cu.hh[0]; av[1] = cu.hh[1];
            accA = __builtin_amdgcn_mfma_f32_32x32x16_f16(av, bnc, accA, 0, 0, 0);
            accB = __builtin_amdgcn_mfma_f32_32x32x16_f16(av, bnc, accB, 0, 0, 0);
        }

        const int mbase = t * 32 + hi4;  // LOCAL index within the split
#pragma unroll
        for (int j = 0; j < 16; ++j) {
            const float a = accA[j];
            if (__any(a > kA2)) {
                const int m = mbase + (j & 3) + 8 * (j >> 2);
                const bool g0 = a > kA0, g1 = a > kA1, g2 = a > kA2;
                kA2 = g1 ? kA1 : (g2 ? a : kA2); iA2 = g1 ? iA1 : (g2 ? m : iA2);
                kA1 = g0 ? kA0 : (g1 ? a : kA1); iA1 = g0 ? iA0 : (g1 ? m : iA1);
                kA0 = g0 ? a : kA0;              iA0 = g0 ? m : iA0;
            }
        }
#pragma unroll
        for (int j = 0; j < 16; ++j) {
            const float a = accB[j];
            if (__any(a > kB2)) {
                const int m = mbase + (j & 3) + 8 * (j >> 2);
                const bool g0 = a > kB0, g1 = a > kB1, g2 = a > kB2;
                kB2 = g1 ? kB1 : (g2 ? a : kB2); iB2 = g1 ? iB1 : (g2 ? m : iB2);
                kB1 = g0 ? kB0 : (g1 ? a : kB1); iB1 = g0 ? iB0 : (g1 ? m : iB1);
                kB0 = g0 ? a : kB0;              iB0 = g0 ? m : iB0;
            }
        }
        __syncthreads();  // all reads of buf[bi] done; stage into it next iter
    }

    // per-group: merge lane-halves (disjoint candidates) lexicographically, store
#pragma unroll
    for (int grp = 0; grp < 2; ++grp) {
        float K0 = grp ? kB0 : kA0, K1 = grp ? kB1 : kA1, K2 = grp ? kB2 : kA2;
        int I0 = grp ? iB0 : iA0, I1 = grp ? iB1 : iA1, I2 = grp ? iB2 : iA2;
        const float ok0 = __shfl_xor(K0, 32), ok1 = __shfl_xor(K1, 32), ok2 = __shfl_xor(K2, 32);
        const int oi0 = __shfl_xor(I0, 32), oi1 = __shfl_xor(I1, 32), oi2 = __shfl_xor(I2, 32);
        const float ck[3] = {ok0, ok1, ok2};
        const int cix[3] = {oi0, oi1, oi2};
#pragma unroll
        for (int r = 0; r < 3; ++r) {
            const float c = ck[r]; const int ci = cix[r];
            const bool b0 = (c > K0) || (c == K0 && ci < I0);
            const bool b1 = (c > K1) || (c == K1 && ci < I1);
            const bool b2 = (c > K2) || (c == K2 && ci < I2);
            K2 = b1 ? K1 : (b2 ? c : K2); I2 = b1 ? I1 : (b2 ? ci : I2);
            K1 = b0 ? K0 : (b1 ? c : K1); I1 = b0 ? I0 : (b1 ? ci : I1);
            K0 = b0 ? c : K0;             I0 = b0 ? ci : I0;
        }
        if (lane < 32) {
            const int q = (grp ? qgB : qgA) * 32 + lane;
            uint4 v;
            v.x = __float_as_uint(K0);
            v.y = __float_as_uint(K1);
            v.z = __float_as_uint(K2);
            v.w = (unsigned)I0 | ((unsigned)I1 << 8) | ((unsigned)I2 << 16);
            pk[((size_t)b * SPL + s) * NN + q] = v;
        }
    }
}

// ---------------------------------------------------------------------------
// K3: merge SPL packed top-3 lists, (key desc, global idx asc) lexicographic.
// Global idx = local (8-bit) + s*256.
// ---------------------------------------------------------------------------
__global__ __launch_bounds__(256) void k_merge(const uint4* __restrict__ pk,
                                               int* __restrict__ fi) {
    const int t = blockIdx.x * 256 + threadIdx.x;
    if (t >= BB * NN) return;
    const int b = t / NN, n = t % NN;
    float dv[3 * SPL]; int iv[3 * SPL];
#pragma unroll
    for (int s = 0; s < SPL; ++s) {
        const uint4 v = pk[((size_t)b * SPL + s) * NN + n];
        dv[s * 3 + 0] = __uint_as_float(v.x);
        dv[s * 3 + 1] = __uint_as_float(v.y);
        dv[s * 3 + 2] = __uint_as_float(v.z);
        iv[s * 3 + 0] = (int)(v.w & 255u) + s * 256;
        iv[s * 3 + 1] = (int)((v.w >> 8) & 255u) + s * 256;
        iv[s * 3 + 2] = (int)((v.w >> 16) & 255u) + s * 256;
    }
    float bd = FLT_MAX; int bi = -1;
#pragma unroll
    for (int r = 0; r < 3; ++r) {
        float ck = -FLT_MAX; int ci = 0x7fffffff;
#pragma unroll
        for (int j = 0; j < 3 * SPL; ++j) {
            const bool after_prev = (dv[j] < bd) || (dv[j] == bd && iv[j] > bi);
            const bool better = (dv[j] > ck) || (dv[j] == ck && iv[j] < ci);
            if (after_prev && better) { ck = dv[j]; ci = iv[j]; }
        }
        fi[(size_t)t * 3 + r] = ci;
        bd = ck; bi = ci;
    }
}

// ---------------------------------------------------------------------------
// K4: MFMA conv. Block = 64 points x 64 co, 4 waves. A = gathered hi-fp16
// fragments straight from xe (kb 0..3), B = pre-packed Wf.
// Epilogue: bias + relu -> padded LDS transpose -> coalesced stores.
// ---------------------------------------------------------------------------
__global__ __launch_bounds__(256) void k_conv(const uint4* __restrict__ xe,
                                              const uint4* __restrict__ Wf,
                                              const int* __restrict__ fi,
                                              const float* __restrict__ bias,
                                              float* __restrict__ out) {
    __shared__ float ot[64][65];
    const int b = blockIdx.y;
    const int n0 = blockIdx.x * 64;
    const int tid = threadIdx.x;
    const int l = tid & 63;
    const int w = tid >> 6;
    const int mt = w >> 1, ct2 = w & 1;
    const int p31 = l & 31, kh = l >> 5;
    const int npt = n0 + mt * 32 + p31;

    f32x16 acc = {};
    const uint4* xb = xe + (size_t)b * 64 * 8 * 64;
    const int fbase3 = (b * NN + npt) * KNN;
#pragma unroll
    for (int kk = 0; kk < KNN; ++kk) {
        const int src = fi[fbase3 + kk];
        const uint4* ap = xb + (size_t)(src >> 5) * 512 + (src & 31) + 32 * kh;
        uint4 af[4], bw[4];
#pragma unroll
        for (int kb = 0; kb < 4; ++kb) af[kb] = ap[(size_t)kb * 64];
#pragma unroll
        for (int kb = 0; kb < 4; ++kb) bw[kb] = Wf[((kk * 2 + ct2) * 4 + kb) * 64 + l];
#pragma unroll
        for (int kb = 0; kb < 4; ++kb) {
            u4h8 ua, ub;
            ua.v = af[kb]; ub.v = bw[kb];
            acc = __builtin_amdgcn_mfma_f32_32x32x16_f16(ua.h, ub.h, acc, 0, 0, 0);
        }
    }
    const int co = ct2 * 32 + p31;
    const float bv = bias[co];
#pragma unroll
    for (int j = 0; j < 16; ++j) {
        const int pt = mt * 32 + (j & 3) + 8 * (j >> 2) + 4 * kh;
        ot[co][pt] = fmaxf(acc[j] + bv, 0.f);
    }
    __syncthreads();
#pragma unroll
    for (int i = 0; i < 16; ++i) {
        const int v = tid + 256 * i;
        const int co2 = v >> 6, col = v & 63;
        out[((size_t)(b * COUT + co2)) * NN + n0 + col] = ot[co2][col];
    }
}

extern "C" void kernel_launch(void* const* d_in, const int* in_sizes, int n_in,
                              void* d_out, int out_size, void* d_ws, size_t ws_size,
                              hipStream_t stream) {
    const float* x = (const float*)d_in[0];
    const float* W = (const float*)d_in[1];
    const float* bias = (const float*)d_in[2];
    float* out = (float*)d_out;

    char* ws = (char*)d_ws;
    uint4* xe = (uint4*)(ws);                       //  8,388,608 B
    unsigned* anc = (unsigned*)(ws + 8388608);      //    131,072 B
    uint4* Wf = (uint4*)(ws + 8519680);             //     24,576 B
    uint4* pk = (uint4*)(ws + 8544256);             //  4,194,304 B
    int* fi = (int*)(ws + 12738560);                //    393,216 B (end ~13.1 MB)

    k_prep<<<dim3(BB, NN / 64), 256, 0, stream>>>(x, xe, anc);
    k_wprep<<<1, 256, 0, stream>>>(W, Wf);
    k_top3<<<dim3(8, SPL, BB), 256, 0, stream>>>(xe, anc, pk);
    k_merge<<<(BB * NN + 255) / 256, 256, 0, stream>>>(pk, fi);
    k_conv<<<dim3(NN / 64, BB), 256, 0, stream>>>(xe, Wf, fi, bias, out);
}

// Round 10
// 79.938 us; speedup vs baseline: 1.0273x; 1.0273x over previous
//
#include <hip/hip_runtime.h>
#include <float.h>

#define BB 16
#define CC 64
#define NN 2048
#define KNN 3
#define COUT 64
#define SPL 8   // candidate-range splits; 256 candidates/split -> 8-bit local idx

typedef _Float16 half8 __attribute__((ext_vector_type(8)));
typedef float f32x16 __attribute__((ext_vector_type(16)));

union u4h8 { uint4 v; half8 h; };

// async global->LDS, 16B per lane, wave-uniform LDS base (HW adds lane*16)
__device__ __forceinline__ void gl_lds16(const void* g, void* l) {
    __builtin_amdgcn_global_load_lds(
        (const __attribute__((address_space(1))) unsigned*)g,
        (__attribute__((address_space(3))) unsigned*)l, 16, 0, 0);
}

// ---------------------------------------------------------------------------
// K1: from x[b][c][n] produce:
//   xe[b][ct][kblk][lane] (16B fp16x8 MFMA fragments of ext=[hi|lo], K=128)
//   anc[b][ct][l<32] (packed fp16 pair (-nc/2 hi, -nc/2 lo))
// Fragment convention: row m = lane&31, k = kblk*16 + 8*(lane>>5) + j.
// kblk 0..3 = hi(x[c]) (c = k), kblk 4..7 = lo residual (c = k-64).
// ---------------------------------------------------------------------------
__global__ __launch_bounds__(256) void k_prep(const float* __restrict__ x,
                                              uint4* __restrict__ xe,
                                              unsigned* __restrict__ anc) {
    __shared__ float t[64][65];
    __shared__ float nsh[64];
    const int b = blockIdx.x;
    const int n0 = blockIdx.y * 64;
    const int tid = threadIdx.x;
    const int ln = tid & 63, g = tid >> 6;
#pragma unroll
    for (int i = 0; i < 16; ++i) {
        const int c = g + 4 * i;
        t[c][ln] = x[((size_t)b * CC + c) * NN + n0 + ln];
    }
    __syncthreads();
    if (tid < 64) {
        float s = 0.f;
#pragma unroll
        for (int c = 0; c < 64; ++c) s = fmaf(t[c][tid], t[c][tid], s);
        nsh[tid] = s;
    }
    // fragment packing: 1024 16B chunks per 64-point group
#pragma unroll
    for (int i = 0; i < 4; ++i) {
        const int cid = tid + 256 * i;
        const int lane = cid & 63;
        const int kblk = (cid >> 6) & 7;
        const int ctl = cid >> 9;               // 0..1
        const int m = ctl * 32 + (lane & 31);   // local point
        const int khalf = (lane >> 5) * 8;
        union { uint4 v; _Float16 h[8]; } pk;
#pragma unroll
        for (int j = 0; j < 8; ++j) {
            const int kg = kblk * 16 + khalf + j;
            const int ch = kg & 63;
            const float f = t[ch][m];
            const _Float16 hi = (_Float16)f;
            pk.h[j] = (kg < 64) ? hi : (_Float16)(f - (float)hi);
        }
        const int ct = (n0 >> 5) + ctl;
        xe[((size_t)(b * 64 + ct) * 8 + kblk) * 64 + lane] = pk.v;
    }
    __syncthreads();
    if (tid < 64) {
        const int ctl = tid >> 5, l = tid & 31;
        const int ct = (n0 >> 5) + ctl;
        const float h = -0.5f * nsh[ctl * 32 + l];
        const _Float16 a0 = (_Float16)h;
        const _Float16 a1 = (_Float16)(h - (float)a0);
        union { unsigned u; _Float16 hh[2]; } cu;
        cu.hh[0] = a0; cu.hh[1] = a1;
        anc[(size_t)(b * 64 + ct) * 32 + l] = cu.u;
    }
}

// ---------------------------------------------------------------------------
// K1b: pack W into fp16 B-fragments. Wf[((kk*2+ct2)*4+kb)*64 + lane]:
// co = ct2*32 + (lane&31), c = kb*16 + 8*(lane>>5) + j, value = fp16(W[co][c][kk])
// ---------------------------------------------------------------------------
__global__ __launch_bounds__(256) void k_wprep(const float* __restrict__ W,
                                               uint4* __restrict__ Wf) {
    const int tid = threadIdx.x;
#pragma unroll
    for (int i = 0; i < 6; ++i) {
        const int id = tid + 256 * i;
        const int l = id & 63;
        const int kb = (id >> 6) & 3;
        const int ct2 = (id >> 8) & 1;
        const int kk = id >> 9;
        const int co = ct2 * 32 + (l & 31);
        union { uint4 v; _Float16 h[8]; } pk;
#pragma unroll
        for (int j = 0; j < 8; ++j) {
            const int c = kb * 16 + 8 * (l >> 5) + j;
            pk.h[j] = (_Float16)W[(co * CC + c) * KNN + kk];
        }
        Wf[id] = pk.v;
    }
}

// ---------------------------------------------------------------------------
// K2: MFMA top-3, ONE-SHOT LDS staging. Block = 4 waves x 2 query groups.
// Entire candidate range of the split (8 tiles, 64 KB) staged up-front via
// 16 global_load_lds per wave -> ONE barrier -> 208 uninterrupted MFMA/wave
// from LDS (ds_read_b128 + MFMA, compiler-scheduled lgkmcnt).
// 26 MFMA per tile per wave (hihi/hilo/lohi + norm; lolo dropped, <1e-6).
// 1D grid with bijective XCD swizzle: bid = b*64 + qg*8 + s so the 8 blocks
// sharing a candidate range land on one XCD's L2.
// ---------------------------------------------------------------------------
__global__ __launch_bounds__(256, 2) void k_top3(const uint4* __restrict__ xe,
                                                 const unsigned* __restrict__ anc,
                                                 uint4* __restrict__ pk) {
    __shared__ uint4 buf[4096];  // 64 KB: [tile 0..7][kblk 0..7][lane 0..63]
    const int bid = blockIdx.x;
    const int s = bid & 7;            // bid = b*64 + qg*8 + s
    const int qgB8 = (bid >> 3) & 7;  // query-group block
    const int b = bid >> 6;

    const int tid = threadIdx.x;
    const int lane = tid & 63;
    const int w = tid >> 6;
    const int wq = qgB8 * 4 + w;                 // 0..31
    const int qgA = wq * 2, qgB = wq * 2 + 1;

    constexpr int TILES = NN / 32 / SPL;  // 8
    const int ct0 = s * TILES;
    const uint4* xb = xe + (size_t)(b * 64) * 512;  // tile stride = 8*64 uint4

    // stage all 8 tiles (64 chunks of 1 KB; 16 per wave), then queries + anc
    const uint4* gsrc = xb + (size_t)ct0 * 512;
#pragma unroll
    for (int i = 0; i < 16; ++i) {
        const int c = w * 16 + i;
        gl_lds16(gsrc + (size_t)c * 64 + lane, &buf[c * 64]);
    }

    half8 bqA[8], bqB[8];
#pragma unroll
    for (int kb = 0; kb < 8; ++kb) {
        u4h8 tA, tB;
        tA.v = xe[((size_t)(b * 64 + qgA) * 8 + kb) * 64 + lane];
        tB.v = xe[((size_t)(b * 64 + qgB) * 8 + kb) * 64 + lane];
        bqA[kb] = tA.h; bqB[kb] = tB.h;
    }
    unsigned av_u[TILES];
#pragma unroll
    for (int t = 0; t < TILES; ++t)
        av_u[t] = anc[(size_t)(b * 64 + ct0 + t) * 32 + (lane & 31)];

    half8 bnc = {};
    if (lane < 32) { bnc[0] = (_Float16)1.0f; bnc[1] = (_Float16)1.0f; }

    float kA0 = -FLT_MAX, kA1 = -FLT_MAX, kA2 = -FLT_MAX;
    float kB0 = -FLT_MAX, kB1 = -FLT_MAX, kB2 = -FLT_MAX;
    int iA0 = -1, iA1 = -1, iA2 = -1;
    int iB0 = -1, iB1 = -1, iB2 = -1;
    const int hi4 = (lane >> 5) * 4;

    __syncthreads();  // drains the global_load_lds queue once

#pragma unroll
    for (int t = 0; t < TILES; ++t) {
        f32x16 accA = {}, accB = {};
        {   // hi fragments: feed hihi + hilo (16 MFMA)
            u4h8 ah[4];
#pragma unroll
            for (int kb = 0; kb < 4; ++kb) ah[kb].v = buf[(t * 8 + kb) * 64 + lane];
#pragma unroll
            for (int kb = 0; kb < 4; ++kb) {
                accA = __builtin_amdgcn_mfma_f32_32x32x16_f16(ah[kb].h, bqA[kb], accA, 0, 0, 0);
                accB = __builtin_amdgcn_mfma_f32_32x32x16_f16(ah[kb].h, bqB[kb], accB, 0, 0, 0);
            }
#pragma unroll
            for (int kb = 0; kb < 4; ++kb) {
                accA = __builtin_amdgcn_mfma_f32_32x32x16_f16(ah[kb].h, bqA[kb + 4], accA, 0, 0, 0);
                accB = __builtin_amdgcn_mfma_f32_32x32x16_f16(ah[kb].h, bqB[kb + 4], accB, 0, 0, 0);
            }
        }
        {   // lo fragments: feed lohi (8 MFMA) + norm fold (2)
            u4h8 al[4];
#pragma unroll
            for (int kb = 0; kb < 4; ++kb) al[kb].v = buf[(t * 8 + 4 + kb) * 64 + lane];
#pragma unroll
            for (int kb = 0; kb < 4; ++kb) {
                accA = __builtin_amdgcn_mfma_f32_32x32x16_f16(al[kb].h, bqA[kb], accA, 0, 0, 0);
                accB = __builtin_amdgcn_mfma_f32_32x32x16_f16(al[kb].h, bqB[kb], accB, 0, 0, 0);
            }
            half8 av = {};
            union { unsigned u; _Float16 hh[2]; } cu;
            cu.u = av_u[t];
            av[0] = cu.hh[0]; av[1] = cu.hh[1];
            accA = __builtin_amdgcn_mfma_f32_32x32x16_f16(av, bnc, accA, 0, 0, 0);
            accB = __builtin_amdgcn_mfma_f32_32x32x16_f16(av, bnc, accB, 0, 0, 0);
        }

        const int mbase = t * 32 + hi4;  // LOCAL index within the split
#pragma unroll
        for (int j = 0; j < 16; ++j) {
            const float a = accA[j];
            if (__any(a > kA2)) {
                const int m = mbase + (j & 3) + 8 * (j >> 2);
                const bool g0 = a > kA0, g1 = a > kA1, g2 = a > kA2;
                kA2 = g1 ? kA1 : (g2 ? a : kA2); iA2 = g1 ? iA1 : (g2 ? m : iA2);
                kA1 = g0 ? kA0 : (g1 ? a : kA1); iA1 = g0 ? iA0 : (g1 ? m : iA1);
                kA0 = g0 ? a : kA0;              iA0 = g0 ? m : iA0;
            }
        }
#pragma unroll
        for (int j = 0; j < 16; ++j) {
            const float a = accB[j];
            if (__any(a > kB2)) {
                const int m = mbase + (j & 3) + 8 * (j >> 2);
                const bool g0 = a > kB0, g1 = a > kB1, g2 = a > kB2;
                kB2 = g1 ? kB1 : (g2 ? a : kB2); iB2 = g1 ? iB1 : (g2 ? m : iB2);
                kB1 = g0 ? kB0 : (g1 ? a : kB1); iB1 = g0 ? iB0 : (g1 ? m : iB1);
                kB0 = g0 ? a : kB0;              iB0 = g0 ? m : iB0;
            }
        }
    }

    // per-group: merge lane-halves (disjoint candidates) lexicographically, store
#pragma unroll
    for (int grp = 0; grp < 2; ++grp) {
        float K0 = grp ? kB0 : kA0, K1 = grp ? kB1 : kA1, K2 = grp ? kB2 : kA2;
        int I0 = grp ? iB0 : iA0, I1 = grp ? iB1 : iA1, I2 = grp ? iB2 : iA2;
        const float ok0 = __shfl_xor(K0, 32), ok1 = __shfl_xor(K1, 32), ok2 = __shfl_xor(K2, 32);
        const int oi0 = __shfl_xor(I0, 32), oi1 = __shfl_xor(I1, 32), oi2 = __shfl_xor(I2, 32);
        const float ck[3] = {ok0, ok1, ok2};
        const int cix[3] = {oi0, oi1, oi2};
#pragma unroll
        for (int r = 0; r < 3; ++r) {
            const float c = ck[r]; const int ci = cix[r];
            const bool b0 = (c > K0) || (c == K0 && ci < I0);
            const bool b1 = (c > K1) || (c == K1 && ci < I1);
            const bool b2 = (c > K2) || (c == K2 && ci < I2);
            K2 = b1 ? K1 : (b2 ? c : K2); I2 = b1 ? I1 : (b2 ? ci : I2);
            K1 = b0 ? K0 : (b1 ? c : K1); I1 = b0 ? I0 : (b1 ? ci : I1);
            K0 = b0 ? c : K0;             I0 = b0 ? ci : I0;
        }
        if (lane < 32) {
            const int q = (grp ? qgB : qgA) * 32 + lane;
            uint4 v;
            v.x = __float_as_uint(K0);
            v.y = __float_as_uint(K1);
            v.z = __float_as_uint(K2);
            v.w = (unsigned)I0 | ((unsigned)I1 << 8) | ((unsigned)I2 << 16);
            pk[((size_t)b * SPL + s) * NN + q] = v;
        }
    }
}

// ---------------------------------------------------------------------------
// K3: merge SPL packed top-3 lists, (key desc, global idx asc) lexicographic.
// Global idx = local (8-bit) + s*256.
// ---------------------------------------------------------------------------
__global__ __launch_bounds__(256) void k_merge(const uint4* __restrict__ pk,
                                               int* __restrict__ fi) {
    const int t = blockIdx.x * 256 + threadIdx.x;
    if (t >= BB * NN) return;
    const int b = t / NN, n = t % NN;
    float dv[3 * SPL]; int iv[3 * SPL];
#pragma unroll
    for (int s = 0; s < SPL; ++s) {
        const uint4 v = pk[((size_t)b * SPL + s) * NN + n];
        dv[s * 3 + 0] = __uint_as_float(v.x);
        dv[s * 3 + 1] = __uint_as_float(v.y);
        dv[s * 3 + 2] = __uint_as_float(v.z);
        iv[s * 3 + 0] = (int)(v.w & 255u) + s * 256;
        iv[s * 3 + 1] = (int)((v.w >> 8) & 255u) + s * 256;
        iv[s * 3 + 2] = (int)((v.w >> 16) & 255u) + s * 256;
    }
    float bd = FLT_MAX; int bi = -1;
#pragma unroll
    for (int r = 0; r < 3; ++r) {
        float ck = -FLT_MAX; int ci = 0x7fffffff;
#pragma unroll
        for (int j = 0; j < 3 * SPL; ++j) {
            const bool after_prev = (dv[j] < bd) || (dv[j] == bd && iv[j] > bi);
            const bool better = (dv[j] > ck) || (dv[j] == ck && iv[j] < ci);
            if (after_prev && better) { ck = dv[j]; ci = iv[j]; }
        }
        fi[(size_t)t * 3 + r] = ci;
        bd = ck; bi = ci;
    }
}

// ---------------------------------------------------------------------------
// K4: MFMA conv. Block = 64 points x 64 co, 4 waves. A = gathered hi-fp16
// fragments straight from xe (kb 0..3), B = pre-packed Wf.
// Epilogue: bias + relu -> padded LDS transpose -> coalesced stores.
// ---------------------------------------------------------------------------
__global__ __launch_bounds__(256) void k_conv(const uint4* __restrict__ xe,
                                              const uint4* __restrict__ Wf,
                                              const int* __restrict__ fi,
                                              const float* __restrict__ bias,
                                              float* __restrict__ out) {
    __shared__ float ot[64][65];
    const int b = blockIdx.y;
    const int n0 = blockIdx.x * 64;
    const int tid = threadIdx.x;
    const int l = tid & 63;
    const int w = tid >> 6;
    const int mt = w >> 1, ct2 = w & 1;
    const int p31 = l & 31, kh = l >> 5;
    const int npt = n0 + mt * 32 + p31;

    f32x16 acc = {};
    const uint4* xb = xe + (size_t)b * 64 * 8 * 64;
    const int fbase3 = (b * NN + npt) * KNN;
#pragma unroll
    for (int kk = 0; kk < KNN; ++kk) {
        const int src = fi[fbase3 + kk];
        const uint4* ap = xb + (size_t)(src >> 5) * 512 + (src & 31) + 32 * kh;
        uint4 af[4], bw[4];
#pragma unroll
        for (int kb = 0; kb < 4; ++kb) af[kb] = ap[(size_t)kb * 64];
#pragma unroll
        for (int kb = 0; kb < 4; ++kb) bw[kb] = Wf[((kk * 2 + ct2) * 4 + kb) * 64 + l];
#pragma unroll
        for (int kb = 0; kb < 4; ++kb) {
            u4h8 ua, ub;
            ua.v = af[kb]; ub.v = bw[kb];
            acc = __builtin_amdgcn_mfma_f32_32x32x16_f16(ua.h, ub.h, acc, 0, 0, 0);
        }
    }
    const int co = ct2 * 32 + p31;
    const float bv = bias[co];
#pragma unroll
    for (int j = 0; j < 16; ++j) {
        const int pt = mt * 32 + (j & 3) + 8 * (j >> 2) + 4 * kh;
        ot[co][pt] = fmaxf(acc[j] + bv, 0.f);
    }
    __syncthreads();
#pragma unroll
    for (int i = 0; i < 16; ++i) {
        const int v = tid + 256 * i;
        const int co2 = v >> 6, col = v & 63;
        out[((size_t)(b * COUT + co2)) * NN + n0 + col] = ot[co2][col];
    }
}

extern "C" void kernel_launch(void* const* d_in, const int* in_sizes, int n_in,
                              void* d_out, int out_size, void* d_ws, size_t ws_size,
                              hipStream_t stream) {
    const float* x = (const float*)d_in[0];
    const float* W = (const float*)d_in[1];
    const float* bias = (const float*)d_in[2];
    float* out = (float*)d_out;

    char* ws = (char*)d_ws;
    uint4* xe = (uint4*)(ws);                       //  8,388,608 B
    unsigned* anc = (unsigned*)(ws + 8388608);      //    131,072 B
    uint4* Wf = (uint4*)(ws + 8519680);             //     24,576 B
    uint4* pk = (uint4*)(ws + 8544256);             //  4,194,304 B
    int* fi = (int*)(ws + 12738560);                //    393,216 B (end ~13.1 MB)

    k_prep<<<dim3(BB, NN / 64), 256, 0, stream>>>(x, xe, anc);
    k_wprep<<<1, 256, 0, stream>>>(W, Wf);
    k_top3<<<dim3(BB * 8 * SPL), 256, 0, stream>>>(xe, anc, pk);
    k_merge<<<(BB * NN + 255) / 256, 256, 0, stream>>>(pk, fi);
    k_conv<<<dim3(NN / 64, BB), 256, 0, stream>>>(xe, Wf, fi, bias, out);
}

// Round 11
// 70.110 us; speedup vs baseline: 1.1712x; 1.1402x over previous
//
#include <hip/hip_runtime.h>
#include <float.h>

#define BB 16
#define CC 64
#define NN 2048
#define KNN 3
#define COUT 64
#define SPL 4      // candidate splits; 512 cands/split -> 9-bit local idx
#define TILES 16   // 32-cand tiles per split

typedef _Float16 half8 __attribute__((ext_vector_type(8)));
typedef float f32x16 __attribute__((ext_vector_type(16)));

union u4h8 { uint4 v; half8 h; };

// async global->LDS, 16B per lane, wave-uniform LDS base (HW adds lane*16)
__device__ __forceinline__ void gl_lds16(const void* g, void* l) {
    __builtin_amdgcn_global_load_lds(
        (const __attribute__((address_space(1))) unsigned*)g,
        (__attribute__((address_space(3))) unsigned*)l, 16, 0, 0);
}

// ---------------------------------------------------------------------------
// K1: from x[b][c][n] produce:
//   xe[b][ct][kblk][lane] (16B fp16x8 MFMA fragments of ext=[hi|lo], K=128)
//   anc[b][ct][l<32] (packed fp16 pair (-nc/2 hi, -nc/2 lo))
// Fragment convention: row m = lane&31, k = kblk*16 + 8*(lane>>5) + j.
// kblk 0..3 = hi(x[c]) (c = k), kblk 4..7 = lo residual (c = k-64).
// ---------------------------------------------------------------------------
__global__ __launch_bounds__(256) void k_prep(const float* __restrict__ x,
                                              uint4* __restrict__ xe,
                                              unsigned* __restrict__ anc) {
    __shared__ float t[64][65];
    __shared__ float nsh[64];
    const int b = blockIdx.x;
    const int n0 = blockIdx.y * 64;
    const int tid = threadIdx.x;
    const int ln = tid & 63, g = tid >> 6;
#pragma unroll
    for (int i = 0; i < 16; ++i) {
        const int c = g + 4 * i;
        t[c][ln] = x[((size_t)b * CC + c) * NN + n0 + ln];
    }
    __syncthreads();
    if (tid < 64) {
        float s = 0.f;
#pragma unroll
        for (int c = 0; c < 64; ++c) s = fmaf(t[c][tid], t[c][tid], s);
        nsh[tid] = s;
    }
#pragma unroll
    for (int i = 0; i < 4; ++i) {
        const int cid = tid + 256 * i;
        const int lane = cid & 63;
        const int kblk = (cid >> 6) & 7;
        const int ctl = cid >> 9;               // 0..1
        const int m = ctl * 32 + (lane & 31);   // local point
        const int khalf = (lane >> 5) * 8;
        union { uint4 v; _Float16 h[8]; } pk;
#pragma unroll
        for (int j = 0; j < 8; ++j) {
            const int kg = kblk * 16 + khalf + j;
            const int ch = kg & 63;
            const float f = t[ch][m];
            const _Float16 hi = (_Float16)f;
            pk.h[j] = (kg < 64) ? hi : (_Float16)(f - (float)hi);
        }
        const int ct = (n0 >> 5) + ctl;
        xe[((size_t)(b * 64 + ct) * 8 + kblk) * 64 + lane] = pk.v;
    }
    __syncthreads();
    if (tid < 64) {
        const int ctl = tid >> 5, l = tid & 31;
        const int ct = (n0 >> 5) + ctl;
        const float h = -0.5f * nsh[ctl * 32 + l];
        const _Float16 a0 = (_Float16)h;
        const _Float16 a1 = (_Float16)(h - (float)a0);
        union { unsigned u; _Float16 hh[2]; } cu;
        cu.hh[0] = a0; cu.hh[1] = a1;
        anc[(size_t)(b * 64 + ct) * 32 + l] = cu.u;
    }
}

// ---------------------------------------------------------------------------
// K1b: pack W into fp16 B-fragments. Wf[((kk*2+ct2)*4+kb)*64 + lane]:
// co = ct2*32 + (lane&31), c = kb*16 + 8*(lane>>5) + j, value = fp16(W[co][c][kk])
// ---------------------------------------------------------------------------
__global__ __launch_bounds__(256) void k_wprep(const float* __restrict__ W,
                                               uint4* __restrict__ Wf) {
    const int tid = threadIdx.x;
#pragma unroll
    for (int i = 0; i < 6; ++i) {
        const int id = tid + 256 * i;
        const int l = id & 63;
        const int kb = (id >> 6) & 3;
        const int ct2 = (id >> 8) & 1;
        const int kk = id >> 9;
        const int co = ct2 * 32 + (l & 31);
        union { uint4 v; _Float16 h[8]; } pk;
#pragma unroll
        for (int j = 0; j < 8; ++j) {
            const int c = kb * 16 + 8 * (l >> 5) + j;
            pk.h[j] = (_Float16)W[(co * CC + c) * KNN + kk];
        }
        Wf[id] = pk.v;
    }
}

// ---------------------------------------------------------------------------
// K2: MFMA top-3, QG=1 per wave (small register contract the compiler keeps:
// bq 32 + acc 16 + av_u 16 + sort 12 + transients ~ 107 VGPR).
// Block = 8 waves sharing a depth-1 LDS double-buffer of candidate tiles;
// 1 global_load_lds per wave per tile, issued one tile ahead of use.
// 13 MFMA/tile (hihi 4, hilo 4, lohi 4, norm 1; lolo < 1e-6, dropped).
// Max-screen gates the insertion scan (15 v_max + 1 __any in common case).
// bid = qb*64 + (b*4+s): blocks sharing candidate range (b,s) share XCD.
// ---------------------------------------------------------------------------
__global__ __launch_bounds__(512, 4) void k_top3(const uint4* __restrict__ xe,
                                                 const unsigned* __restrict__ anc,
                                                 uint4* __restrict__ pk) {
    __shared__ uint4 buf[2][8][64];  // 2 x 8KB candidate tiles
    const int bid = blockIdx.x;      // 512 blocks
    const int qb = bid >> 6;         // query block 0..7
    const int rem = bid & 63;
    const int b = rem >> 2;
    const int s = rem & 3;

    const int tid = threadIdx.x;
    const int lane = tid & 63;
    const int w = tid >> 6;          // wave 0..7
    const int qg = qb * 8 + w;       // this wave's query group (32 queries)

    const uint4* xb = xe + (size_t)(b * 64) * 512;  // tile stride 8*64 uint4
    const int ct0 = s * TILES;

    // prologue: stage tile 0 (1 KB chunk per wave)
    gl_lds16(xb + ((size_t)ct0 * 8 + w) * 64 + lane, &buf[0][w][0]);

    half8 bq[8];
#pragma unroll
    for (int kb = 0; kb < 8; ++kb) {
        u4h8 tq;
        tq.v = xe[((size_t)(b * 64 + qg) * 8 + kb) * 64 + lane];
        bq[kb] = tq.h;
    }
    unsigned av_u[TILES];
#pragma unroll
    for (int t = 0; t < TILES; ++t)
        av_u[t] = anc[(size_t)(b * 64 + ct0 + t) * 32 + (lane & 31)];

    half8 bnc = {};
    if (lane < 32) { bnc[0] = (_Float16)1.0f; bnc[1] = (_Float16)1.0f; }

    float k0 = -FLT_MAX, k1 = -FLT_MAX, k2 = -FLT_MAX;
    int i0 = -1, i1 = -1, i2 = -1;
    const int hi4 = (lane >> 5) * 4;

    __syncthreads();

#pragma unroll
    for (int t = 0; t < TILES; ++t) {
        const int bi = t & 1;
        if (t + 1 < TILES)  // stage next tile into the buffer freed at t-1
            gl_lds16(xb + ((size_t)(ct0 + t + 1) * 8 + w) * 64 + lane,
                     &buf[bi ^ 1][w][0]);

        f32x16 acc = {};
        {
            u4h8 ah[4];
#pragma unroll
            for (int kb = 0; kb < 4; ++kb) ah[kb].v = buf[bi][kb][lane];
#pragma unroll
            for (int kb = 0; kb < 4; ++kb)  // hihi
                acc = __builtin_amdgcn_mfma_f32_32x32x16_f16(ah[kb].h, bq[kb], acc, 0, 0, 0);
#pragma unroll
            for (int kb = 0; kb < 4; ++kb)  // hilo
                acc = __builtin_amdgcn_mfma_f32_32x32x16_f16(ah[kb].h, bq[kb + 4], acc, 0, 0, 0);
        }
        {
            u4h8 al[4];
#pragma unroll
            for (int kb = 0; kb < 4; ++kb) al[kb].v = buf[bi][4 + kb][lane];
#pragma unroll
            for (int kb = 0; kb < 4; ++kb)  // lohi
                acc = __builtin_amdgcn_mfma_f32_32x32x16_f16(al[kb].h, bq[kb], acc, 0, 0, 0);
            half8 av = {};
            union { unsigned u; _Float16 hh[2]; } cu;
            cu.u = av_u[t];
            av[0] = cu.hh[0]; av[1] = cu.hh[1];
            acc = __builtin_amdgcn_mfma_f32_32x32x16_f16(av, bnc, acc, 0, 0, 0);
        }

        // branchless tile-max screen, then (rare) exact insertion scan
        float tmax = acc[0];
#pragma unroll
        for (int j = 1; j < 16; ++j) tmax = fmaxf(tmax, acc[j]);
        if (__any(tmax > k2)) {
            const int mbase = t * 32 + hi4;  // LOCAL index within split
#pragma unroll
            for (int j = 0; j < 16; ++j) {
                const float a = acc[j];
                if (__any(a > k2)) {
                    const int m = mbase + (j & 3) + 8 * (j >> 2);
                    const bool g0 = a > k0, g1 = a > k1, g2 = a > k2;
                    k2 = g1 ? k1 : (g2 ? a : k2); i2 = g1 ? i1 : (g2 ? m : i2);
                    k1 = g0 ? k0 : (g1 ? a : k1); i1 = g0 ? i0 : (g1 ? m : i1);
                    k0 = g0 ? a : k0;             i0 = g0 ? m : i0;
                }
            }
        }
        __syncthreads();  // tile t consumed; buffer safe to overwrite
    }

    // merge lane-halves (disjoint candidate rows) lexicographically
    const float ok0 = __shfl_xor(k0, 32), ok1 = __shfl_xor(k1, 32), ok2 = __shfl_xor(k2, 32);
    const int oi0 = __shfl_xor(i0, 32), oi1 = __shfl_xor(i1, 32), oi2 = __shfl_xor(i2, 32);
    const float ck[3] = {ok0, ok1, ok2};
    const int cix[3] = {oi0, oi1, oi2};
#pragma unroll
    for (int r = 0; r < 3; ++r) {
        const float c = ck[r]; const int ci = cix[r];
        const bool b0 = (c > k0) || (c == k0 && ci < i0);
        const bool b1 = (c > k1) || (c == k1 && ci < i1);
        const bool b2 = (c > k2) || (c == k2 && ci < i2);
        k2 = b1 ? k1 : (b2 ? c : k2); i2 = b1 ? i1 : (b2 ? ci : i2);
        k1 = b0 ? k0 : (b1 ? c : k1); i1 = b0 ? i0 : (b1 ? ci : i1);
        k0 = b0 ? c : k0;             i0 = b0 ? ci : i0;
    }
    if (lane < 32) {
        const int q = qg * 32 + lane;
        uint4 v;
        v.x = __float_as_uint(k0);
        v.y = __float_as_uint(k1);
        v.z = __float_as_uint(k2);
        v.w = (unsigned)i0 | ((unsigned)i1 << 9) | ((unsigned)i2 << 18);  // 27 bits
        pk[((size_t)b * SPL + s) * NN + q] = v;
    }
}

// ---------------------------------------------------------------------------
// K3: merge SPL packed top-3 lists, (key desc, global idx asc) lexicographic.
// Global idx = local (9-bit) + s*512.
// ---------------------------------------------------------------------------
__global__ __launch_bounds__(256) void k_merge(const uint4* __restrict__ pk,
                                               int* __restrict__ fi) {
    const int t = blockIdx.x * 256 + threadIdx.x;
    if (t >= BB * NN) return;
    const int b = t / NN, n = t % NN;
    float dv[3 * SPL]; int iv[3 * SPL];
#pragma unroll
    for (int s = 0; s < SPL; ++s) {
        const uint4 v = pk[((size_t)b * SPL + s) * NN + n];
        dv[s * 3 + 0] = __uint_as_float(v.x);
        dv[s * 3 + 1] = __uint_as_float(v.y);
        dv[s * 3 + 2] = __uint_as_float(v.z);
        iv[s * 3 + 0] = (int)(v.w & 511u) + s * 512;
        iv[s * 3 + 1] = (int)((v.w >> 9) & 511u) + s * 512;
        iv[s * 3 + 2] = (int)((v.w >> 18) & 511u) + s * 512;
    }
    float bd = FLT_MAX; int bi = -1;
#pragma unroll
    for (int r = 0; r < 3; ++r) {
        float ck = -FLT_MAX; int ci = 0x7fffffff;
#pragma unroll
        for (int j = 0; j < 3 * SPL; ++j) {
            const bool after_prev = (dv[j] < bd) || (dv[j] == bd && iv[j] > bi);
            const bool better = (dv[j] > ck) || (dv[j] == ck && iv[j] < ci);
            if (after_prev && better) { ck = dv[j]; ci = iv[j]; }
        }
        fi[(size_t)t * 3 + r] = ci;
        bd = ck; bi = ci;
    }
}

// ---------------------------------------------------------------------------
// K4: MFMA conv. Block = 64 points x 64 co, 4 waves. A = gathered hi-fp16
// fragments straight from xe (kb 0..3), B = pre-packed Wf.
// Epilogue: bias + relu -> padded LDS transpose -> coalesced stores.
// ---------------------------------------------------------------------------
__global__ __launch_bounds__(256) void k_conv(const uint4* __restrict__ xe,
                                              const uint4* __restrict__ Wf,
                                              const int* __restrict__ fi,
                                              const float* __restrict__ bias,
                                              float* __restrict__ out) {
    __shared__ float ot[64][65];
    const int b = blockIdx.y;
    const int n0 = blockIdx.x * 64;
    const int tid = threadIdx.x;
    const int l = tid & 63;
    const int w = tid >> 6;
    const int mt = w >> 1, ct2 = w & 1;
    const int p31 = l & 31, kh = l >> 5;
    const int npt = n0 + mt * 32 + p31;

    f32x16 acc = {};
    const uint4* xb = xe + (size_t)b * 64 * 8 * 64;
    const int fbase3 = (b * NN + npt) * KNN;
#pragma unroll
    for (int kk = 0; kk < KNN; ++kk) {
        const int src = fi[fbase3 + kk];
        const uint4* ap = xb + (size_t)(src >> 5) * 512 + (src & 31) + 32 * kh;
        uint4 af[4], bw[4];
#pragma unroll
        for (int kb = 0; kb < 4; ++kb) af[kb] = ap[(size_t)kb * 64];
#pragma unroll
        for (int kb = 0; kb < 4; ++kb) bw[kb] = Wf[((kk * 2 + ct2) * 4 + kb) * 64 + l];
#pragma unroll
        for (int kb = 0; kb < 4; ++kb) {
            u4h8 ua, ub;
            ua.v = af[kb]; ub.v = bw[kb];
            acc = __builtin_amdgcn_mfma_f32_32x32x16_f16(ua.h, ub.h, acc, 0, 0, 0);
        }
    }
    const int co = ct2 * 32 + p31;
    const float bv = bias[co];
#pragma unroll
    for (int j = 0; j < 16; ++j) {
        const int pt = mt * 32 + (j & 3) + 8 * (j >> 2) + 4 * kh;
        ot[co][pt] = fmaxf(acc[j] + bv, 0.f);
    }
    __syncthreads();
#pragma unroll
    for (int i = 0; i < 16; ++i) {
        const int v = tid + 256 * i;
        const int co2 = v >> 6, col = v & 63;
        out[((size_t)(b * COUT + co2)) * NN + n0 + col] = ot[co2][col];
    }
}

extern "C" void kernel_launch(void* const* d_in, const int* in_sizes, int n_in,
                              void* d_out, int out_size, void* d_ws, size_t ws_size,
                              hipStream_t stream) {
    const float* x = (const float*)d_in[0];
    const float* W = (const float*)d_in[1];
    const float* bias = (const float*)d_in[2];
    float* out = (float*)d_out;

    char* ws = (char*)d_ws;
    uint4* xe = (uint4*)(ws);                       //  8,388,608 B
    unsigned* anc = (unsigned*)(ws + 8388608);      //    131,072 B
    uint4* Wf = (uint4*)(ws + 8519680);             //     24,576 B
    uint4* pk = (uint4*)(ws + 8544256);             //  2,097,152 B
    int* fi = (int*)(ws + 10641408);                //    393,216 B (end ~11.0 MB)

    k_prep<<<dim3(BB, NN / 64), 256, 0, stream>>>(x, xe, anc);
    k_wprep<<<1, 256, 0, stream>>>(W, Wf);
    k_top3<<<dim3(8 * 64), 512, 0, stream>>>(xe, anc, pk);
    k_merge<<<(BB * NN + 255) / 256, 256, 0, stream>>>(pk, fi);
    k_conv<<<dim3(NN / 64, BB), 256, 0, stream>>>(xe, Wf, fi, bias, out);
}